// Round 1
// baseline (120.908 us; speedup 1.0000x reference)
//
#include <hip/hip_runtime.h>

// GraphInteractionNetwork: B=8, P=512, D=16, E=64, H=128
// Algebraic restructuring:
//   h(s,r) = relu(dist(s,r)*w0 + G[s] + br[r]),  G[s] = ns@We1[17:33], br = be1 + nr@We1[1:17]
//   agg[r] = (sum_{s != r} h(s,r)) @ We2 + 511*be2       (relu-sum commutes with 2nd linear)
//   out[r] = relu([agg[r], n[r]] @ Wn1 + bn1) @ Wn2 + bn2

#define Bc 8
#define Pc 512
#define Dc 16
#define Ec 64
#define Hc 128
#define RT 4   // receivers per block

__global__ __launch_bounds__(256) void gin_precompute_G(
    const float* __restrict__ hIn, const float* __restrict__ We1, float* __restrict__ G) {
  // one block = 2 nodes; thread: (node_half, j)
  const int node = blockIdx.x * 2 + (threadIdx.x >> 7);
  const int j = threadIdx.x & (Hc - 1);
  const float* n = hIn + node * Dc;
  float acc = 0.f;
#pragma unroll
  for (int k = 0; k < Dc; ++k) acc = fmaf(n[k], We1[(17 + k) * Hc + j], acc);
  G[node * Hc + j] = acc;
}

__global__ __launch_bounds__(256) void gin_main(
    const float* __restrict__ hIn, const float* __restrict__ We1, const float* __restrict__ be1,
    const float* __restrict__ We2, const float* __restrict__ be2,
    const float* __restrict__ Wn1, const float* __restrict__ bn1,
    const float* __restrict__ Wn2, const float* __restrict__ bn2,
    const float* __restrict__ G, float* __restrict__ out) {
  const int tid  = threadIdx.x;
  const int j    = tid & (Hc - 1);
  const int half = tid >> 7;                 // 0/1: splits the sender loop
  const int blk  = blockIdx.x;               // b * (P/RT) + rb
  const int b    = blk / (Pc / RT);
  const int rb   = blk % (Pc / RT);
  const int r0   = rb * RT;

  const float* nodes = hIn + b * Pc * Dc;
  const float* Gb    = G + b * Pc * Hc;

  __shared__ float s_dist[RT][Pc];      // 8 KB
  __shared__ float s_nr[RT][Dc];        // 256 B
  __shared__ float s_hsum[RT][Hc];      // 2 KB
  __shared__ float s_nin[RT][Ec + Dc];  // 1.25 KB
  __shared__ float s_h2[RT][Hc];        // 2 KB

  // receiver node vectors
  if (tid < RT * Dc) {
    int k = tid / Dc, d = tid % Dc;
    s_nr[k][d] = nodes[(r0 + k) * Dc + d];
  }
  __syncthreads();

  // distances for all (k, s): 2048 values, 8 per thread
  for (int idx = tid; idx < RT * Pc; idx += 256) {
    int k = idx / Pc, s = idx % Pc;
    const float* ns = nodes + s * Dc;
    float acc = 0.f;
#pragma unroll
    for (int d = 0; d < Dc; ++d) {
      float df = ns[d] - s_nr[k][d];
      acc = fmaf(df, df, acc);
    }
    s_dist[k][s] = sqrtf(acc);
  }

  // per-thread receiver biases br[k][j] = be1[j] + nr[k] @ We1[1:17, j]; w0 = We1[0, j]
  const float w0 = We1[j];
  float br[RT];
#pragma unroll
  for (int k = 0; k < RT; ++k) {
    float acc = be1[j];
#pragma unroll
    for (int d = 0; d < Dc; ++d) acc = fmaf(s_nr[k][d], We1[(1 + d) * Hc + j], acc);
    br[k] = acc;
  }
  __syncthreads();  // s_dist ready

  // main sender loop: each half covers 256 senders, thread owns component j for RT receivers
  float acc0 = 0.f, acc1 = 0.f, acc2 = 0.f, acc3 = 0.f;
  const int s_begin = half * (Pc / 2);
#pragma unroll 4
  for (int s = s_begin; s < s_begin + Pc / 2; ++s) {
    float g = Gb[s * Hc + j];
    acc0 += fmaxf(fmaf(s_dist[0][s], w0, g + br[0]), 0.f);
    acc1 += fmaxf(fmaf(s_dist[1][s], w0, g + br[1]), 0.f);
    acc2 += fmaxf(fmaf(s_dist[2][s], w0, g + br[2]), 0.f);
    acc3 += fmaxf(fmaf(s_dist[3][s], w0, g + br[3]), 0.f);
  }

  if (half == 1) {
    s_hsum[0][j] = acc0; s_hsum[1][j] = acc1; s_hsum[2][j] = acc2; s_hsum[3][j] = acc3;
  }
  __syncthreads();
  if (half == 0) {
    float a[RT] = {acc0, acc1, acc2, acc3};
#pragma unroll
    for (int k = 0; k < RT; ++k) {
      // subtract the (s == r_k) self-edge: dist = 0 there
      float corr = fmaxf(Gb[(r0 + k) * Hc + j] + br[k], 0.f);
      s_hsum[k][j] += a[k] - corr;
    }
  }
  __syncthreads();

  // agg[k][e] = s_hsum[k] @ We2[:, e] + 511*be2[e]   (256 threads = 4 k x 64 e)
  {
    int k = tid >> 6, e = tid & (Ec - 1);
    float acc = 511.0f * be2[e];
#pragma unroll 16
    for (int jj = 0; jj < Hc; ++jj) acc = fmaf(s_hsum[k][jj], We2[jj * Ec + e], acc);
    s_nin[k][e] = acc;
  }
  if (tid < RT * Dc) {
    int k = tid / Dc, d = tid % Dc;
    s_nin[k][Ec + d] = s_nr[k][d];
  }
  __syncthreads();

  // hidden: h2[k][j] = relu(n_in[k] @ Wn1[:, j] + bn1[j]); each (j, half) does 2 receivers
#pragma unroll
  for (int kk = 0; kk < RT / 2; ++kk) {
    int k = half * (RT / 2) + kk;
    float acc = bn1[j];
#pragma unroll 16
    for (int i = 0; i < Ec + Dc; ++i) acc = fmaf(s_nin[k][i], Wn1[i * Hc + j], acc);
    s_h2[k][j] = fmaxf(acc, 0.f);
  }
  __syncthreads();

  // out[k][d] = h2[k] @ Wn2[:, d] + bn2[d]   (64 threads)
  if (tid < RT * Dc) {
    int k = tid >> 4, d = tid & (Dc - 1);
    float acc = bn2[d];
#pragma unroll 16
    for (int jj = 0; jj < Hc; ++jj) acc = fmaf(s_h2[k][jj], Wn2[jj * Dc + d], acc);
    out[b * Pc * Dc + (r0 + k) * Dc + d] = acc;
  }
}

extern "C" void kernel_launch(void* const* d_in, const int* in_sizes, int n_in,
                              void* d_out, int out_size, void* d_ws, size_t ws_size,
                              hipStream_t stream) {
  const float* h   = (const float*)d_in[0];
  const float* We1 = (const float*)d_in[1];
  const float* be1 = (const float*)d_in[2];
  const float* We2 = (const float*)d_in[3];
  const float* be2 = (const float*)d_in[4];
  const float* Wn1 = (const float*)d_in[5];
  const float* bn1 = (const float*)d_in[6];
  const float* Wn2 = (const float*)d_in[7];
  const float* bn2 = (const float*)d_in[8];
  float* out = (float*)d_out;
  float* G   = (float*)d_ws;  // B*P*H floats = 2 MB

  gin_precompute_G<<<Bc * Pc / 2, 256, 0, stream>>>(h, We1, G);
  gin_main<<<Bc * Pc / RT, 256, 0, stream>>>(h, We1, be1, We2, be2, Wn1, bn1, Wn2, bn2, G, out);
}